// Round 4
// baseline (9718.836 us; speedup 1.0000x reference)
//
#include <hip/hip_runtime.h>
#include <cstdint>
#include <cstddef>

#define T_STEPS 512
#define BATCH   1024
#define IN_DIM  178
#define NH1     64
#define NG1     256      // 4*H1
#define NH2     32
#define NG2     128      // 4*H2
#define TCHUNK  4
#define NCHUNK  (T_STEPS / TCHUNK)
#define BPW     4        // batch elements per workgroup
#define XROW    (BATCH * IN_DIM)

__device__ __forceinline__ float sigmoidf_(float v) {
    return 1.0f / (1.0f + __expf(-v));
}
__device__ __forceinline__ float tanhf_(float v) {
    return 1.0f - 2.0f / (__expf(2.0f * v) + 1.0f);
}

// Register-budget note (rounds 1-3): the backend pins this kernel at 64 VGPRs
// regardless of __launch_bounds__/waves_per_eu hints. Round 3: wr1[16]+wr2[24]
// persistent -> spills -> 4.6 GB scratch writes at ~1 TB/s = the whole runtime.
// This version splits L2 weights 8-ways (wr2: 24 -> 12 regs) so peak pressure
// fits under 64. Dense head moves to wave-15 stragglers in Phase A.

struct __align__(16) SM {
    float xproj[TCHUNK][BPW][NG1];  // 16 KB  input-proj results (bias included)
    float w1sA[NG1 * 16];           // 16 KB  staging buffer A (swizzled 16B slots)
    union {
        float red[32 * NG2];        // 16 KB  partials: L1 as [16][256], L2 as [32][128]
        float w1sB[NG1 * 16];       //        staging buffer B (aliased)
    } u;
    float h1s[BPW][NH1];            // 1 KB
    float h2s[BPW][NH2];            // 0.5 KB
    float b1s[NG1];
    float b2s[NG2];
    float wds[2 * NH2];
    float bds[4];
};

__device__ __forceinline__ float4 stage_load(const float* __restrict__ w_ih1,
                                             int sg, int k0, bool tail) {
    float4 v;
    if (!tail) {
        const float2* p = (const float2*)(w_ih1 + (size_t)sg * IN_DIM + k0);
        float2 a = p[0], b = p[1];
        v.x = a.x; v.y = a.y; v.z = b.x; v.w = b.y;
    } else {
        v.x = (k0 + 0 < IN_DIM) ? w_ih1[(size_t)sg * IN_DIM + k0 + 0] : 0.0f;
        v.y = (k0 + 1 < IN_DIM) ? w_ih1[(size_t)sg * IN_DIM + k0 + 1] : 0.0f;
        v.z = (k0 + 2 < IN_DIM) ? w_ih1[(size_t)sg * IN_DIM + k0 + 2] : 0.0f;
        v.w = (k0 + 3 < IN_DIM) ? w_ih1[(size_t)sg * IN_DIM + k0 + 3] : 0.0f;
    }
    return v;
}

__device__ __forceinline__ void stage_write(float* buf, int sg, int sslot, float4 v) {
    *(float4*)&buf[sg * 16 + sslot] = v;
}

__device__ __forceinline__ void inproj_compute(const float* __restrict__ xb,
                                               const float* buf, int kb,
                                               int g1, int swz_r,
                                               float acc[TCHUNK], bool tail) {
    #pragma unroll
    for (int c4 = 0; c4 < 4; ++c4) {
        const float4 wv = *(const float4*)&buf[g1 * 16 + (((c4) ^ swz_r) << 2)];
        const int k = kb * 16 + c4 * 4;
        if (!tail) {
            #pragma unroll
            for (int tt = 0; tt < TCHUNK; ++tt) {
                const float2* xp = (const float2*)(xb + (size_t)tt * XROW + k);
                float2 xa = xp[0];
                float2 xc = xp[1];
                acc[tt] += xa.x * wv.x + xa.y * wv.y + xc.x * wv.z + xc.y * wv.w;
            }
        } else if (k < IN_DIM) {
            #pragma unroll
            for (int tt = 0; tt < TCHUNK; ++tt) {
                const float* xp = xb + (size_t)tt * XROW;
                float s = 0.0f;
                if (k + 0 < IN_DIM) s += xp[k + 0] * wv.x;
                if (k + 1 < IN_DIM) s += xp[k + 1] * wv.y;
                acc[tt] += s;   // k+2/k+3 have wv.z=wv.w=0 from padding
            }
        }
    }
}

extern "C" __global__
__attribute__((amdgpu_flat_work_group_size(1024, 1024)))
__attribute__((amdgpu_waves_per_eu(4, 4)))
void lstm_fused_kernel(
    const float* __restrict__ x,
    const float* __restrict__ w_ih1, const float* __restrict__ w_hh1,
    const float* __restrict__ b_ih1, const float* __restrict__ b_hh1,
    const float* __restrict__ w_ih2, const float* __restrict__ w_hh2,
    const float* __restrict__ b_ih2, const float* __restrict__ b_hh2,
    const float* __restrict__ w_dense, const float* __restrict__ b_dense,
    float* __restrict__ out)
{
    __shared__ SM sm;
    const int tid = threadIdx.x;
    const int b0  = blockIdx.x * BPW;

    // ---------------- one-time init ----------------
    if (tid < NG1) sm.b1s[tid] = b_ih1[tid] + b_hh1[tid];
    else if (tid < NG1 + NG2) { int i = tid - NG1; sm.b2s[i] = b_ih2[i] + b_hh2[i]; }
    else if (tid < NG1 + NG2 + 2 * NH2) { int i = tid - NG1 - NG2; sm.wds[i] = w_dense[i]; }
    else if (tid < NG1 + NG2 + 2 * NH2 + 2) { int i = tid - NG1 - NG2 - 2 * NH2; sm.bds[i] = b_dense[i]; }
    if (tid < BPW * NH1) ((float*)sm.h1s)[tid] = 0.0f;
    if (tid < BPW * NH2) ((float*)sm.h2s)[tid] = 0.0f;

    // L1 recurrent weights: thread (g1 = tid&255, kq1 = tid>>8) owns w_hh1[g1][kq1*16 .. +16)
    const int g1  = tid & 255;
    const int kq1 = tid >> 8;
    float wr1[16];
    #pragma unroll
    for (int j = 0; j < 16; ++j) wr1[j] = w_hh1[g1 * NH1 + kq1 * 16 + j];

    // L2 weights (concat [w_ih2 | w_hh2] along k: 96 cols), 8-way k-split:
    // thread (g2 = tid&127, kq2 = tid>>7 in 0..7) owns cols kq2*12 .. +12  (12 regs)
    const int g2  = tid & 127;
    const int kq2 = tid >> 7;
    float wr2[12];
    #pragma unroll
    for (int j = 0; j < 12; ++j) {
        int kk = kq2 * 12 + j;
        wr2[j] = (kk < NH1) ? w_ih2[g2 * NH1 + kk] : w_hh2[g2 * NH2 + (kk - NH1)];
    }

    float c1 = 0.0f;  // tid<256: (b=tid>>6, h=tid&63)
    float c2 = 0.0f;  // tid<128: (b=tid>>5, h=tid&31)

    // staging / in-proj index helpers
    const int sg    = tid >> 2;                      // staging row (0..255)
    const int sc4   = tid & 3;                       // logical 16B slot
    const int sslot = ((sc4 ^ ((sg >> 1) & 3)) << 2);// swizzled float offset
    const int bi_   = tid >> 8;                      // in-proj batch slot (0..3)
    const int swz_r = (g1 >> 1) & 3;                 // reader xor key

    __syncthreads();

    for (int chunk = 0; chunk < NCHUNK; ++chunk) {
        const int t0 = chunk * TCHUNK;

        // ================= input projection for this chunk =================
        float acc[TCHUNK] = {0.f, 0.f, 0.f, 0.f};
        const float* xb = x + ((size_t)t0 * BATCH + (size_t)(b0 + bi_)) * IN_DIM;

        {
            float4 v0 = stage_load(w_ih1, sg, 0, false);
            stage_write(sm.w1sA, sg, sslot, v0);
        }
        __syncthreads();

        #pragma unroll 1
        for (int kb2 = 0; kb2 < 6; ++kb2) {
            const int kbA = 2 * kb2;
            const int kbB = 2 * kb2 + 1;
            const bool tailB = (kbB == 11);

            float4 vB = stage_load(w_ih1, sg, kbB * 16 + sc4 * 4, tailB);
            inproj_compute(xb, sm.w1sA, kbA, g1, swz_r, acc, false);
            stage_write(sm.u.w1sB, sg, sslot, vB);
            __syncthreads();

            const bool haveA2 = (kb2 < 5);
            float4 vA2;
            if (haveA2) vA2 = stage_load(w_ih1, sg, (kbB + 1) * 16 + sc4 * 4, false);
            inproj_compute(xb, sm.u.w1sB, kbB, g1, swz_r, acc, tailB);
            if (haveA2) stage_write(sm.w1sA, sg, sslot, vA2);
            __syncthreads();
        }

        {
            float b1v = sm.b1s[g1];
            #pragma unroll
            for (int tt = 0; tt < TCHUNK; ++tt)
                sm.xproj[tt][bi_][g1] = acc[tt] + b1v;
        }
        __syncthreads();   // protects w1sB(=red) before Phase A writes red

        // ================= TCHUNK recurrent steps =================
        for (int tt = 0; tt < TCHUNK; ++tt) {
            const int t = t0 + tt;

            // ---- Phase A: L1 recurrent partials (all threads); wave-15
            //      stragglers also do the dense head for step t-1 ----
            #pragma unroll
            for (int b = 0; b < BPW; ++b) {
                const float4* hp = (const float4*)&sm.h1s[b][kq1 * 16];  // wave-uniform
                float p = 0.0f;
                #pragma unroll
                for (int j4 = 0; j4 < 4; ++j4) {
                    float4 hv = hp[j4];
                    p += hv.x * wr1[j4 * 4 + 0] + hv.y * wr1[j4 * 4 + 1]
                       + hv.z * wr1[j4 * 4 + 2] + hv.w * wr1[j4 * 4 + 3];
                }
                sm.u.red[(kq1 * 4 + b) * NG1 + g1] = p;   // [16][256]
            }
            if (tid >= 1016) {
                if (t > 0) {   // dense head for t-1 (h2s still holds h2(t-1))
                    const int b = (tid >> 1) & 3, o = tid & 1;
                    float a = sm.bds[o];
                    #pragma unroll
                    for (int k = 0; k < NH2; ++k)
                        a += sigmoidf_(sm.h2s[b][k]) * sm.wds[o * NH2 + k];
                    out[(size_t)(t - 1) * (2 * BATCH) + (size_t)(b0 + b) * 2 + o] = sigmoidf_(a);
                }
            }
            __syncthreads();

            // ---- Phase C: L1 combine + pointwise (tid < 256) ----
            if (tid < 256) {
                const int b = tid >> 6, h = tid & 63;
                float gi = sm.xproj[tt][b][h];
                float gf = sm.xproj[tt][b][64 + h];
                float gg = sm.xproj[tt][b][128 + h];
                float go = sm.xproj[tt][b][192 + h];
                #pragma unroll
                for (int kq = 0; kq < 4; ++kq) {
                    const float* r = &sm.u.red[(kq * 4 + b) * NG1];
                    gi += r[h]; gf += r[64 + h]; gg += r[128 + h]; go += r[192 + h];
                }
                float iv = sigmoidf_(gi);
                float fv = sigmoidf_(gf);
                float gv = tanhf_(gg);
                float ov = sigmoidf_(go);
                c1 = fv * c1 + iv * gv;
                sm.h1s[b][h] = ov * tanhf_(c1);
            }
            __syncthreads();

            // ---- Phase B: L2 partials (ALL 1024 threads, 8-way k-split) ----
            #pragma unroll
            for (int b = 0; b < BPW; ++b) {
                float p = 0.0f;
                #pragma unroll
                for (int j4 = 0; j4 < 3; ++j4) {
                    int kk = kq2 * 12 + j4 * 4;
                    float4 v;
                    if (kk < NH1) {
                        float4 hv = *(const float4*)&sm.h1s[b][kk];    // wave-uniform
                        v.x = fmaxf(hv.x, 0.f); v.y = fmaxf(hv.y, 0.f);
                        v.z = fmaxf(hv.z, 0.f); v.w = fmaxf(hv.w, 0.f);
                    } else {
                        v = *(const float4*)&sm.h2s[b][kk - NH1];      // wave-uniform
                    }
                    p += v.x * wr2[j4 * 4 + 0] + v.y * wr2[j4 * 4 + 1]
                       + v.z * wr2[j4 * 4 + 2] + v.w * wr2[j4 * 4 + 3];
                }
                sm.u.red[(kq2 * 4 + b) * NG2 + g2] = p;   // [32][128]
            }
            __syncthreads();

            // ---- Phase C2: L2 combine + pointwise (tid < 128) ----
            if (tid < 128) {
                const int b = tid >> 5, h = tid & 31;
                float gi = sm.b2s[h];
                float gf = sm.b2s[32 + h];
                float gg = sm.b2s[64 + h];
                float go = sm.b2s[96 + h];
                #pragma unroll
                for (int kq = 0; kq < 8; ++kq) {
                    const float* r = &sm.u.red[(kq * 4 + b) * NG2];
                    gi += r[h]; gf += r[32 + h]; gg += r[64 + h]; go += r[96 + h];
                }
                float iv = sigmoidf_(gi);
                float fv = sigmoidf_(gf);
                float gv = tanhf_(gg);
                float ov = sigmoidf_(go);
                c2 = fv * c2 + iv * gv;
                sm.h2s[b][h] = ov * tanhf_(c2);
            }
            __syncthreads();
        }
    }

    // final dense head for t = 511
    if (tid < 8) {
        const int b = tid >> 1, o = tid & 1;
        float a = sm.bds[o];
        #pragma unroll
        for (int k = 0; k < NH2; ++k)
            a += sigmoidf_(sm.h2s[b][k]) * sm.wds[o * NH2 + k];
        out[(size_t)511 * (2 * BATCH) + (size_t)(b0 + b) * 2 + o] = sigmoidf_(a);
    }
}

extern "C" void kernel_launch(void* const* d_in, const int* in_sizes, int n_in,
                              void* d_out, int out_size, void* d_ws, size_t ws_size,
                              hipStream_t stream) {
    const float* x       = (const float*)d_in[0];
    const float* w_ih1   = (const float*)d_in[1];
    const float* w_hh1   = (const float*)d_in[2];
    const float* b_ih1   = (const float*)d_in[3];
    const float* b_hh1   = (const float*)d_in[4];
    const float* w_ih2   = (const float*)d_in[5];
    const float* w_hh2   = (const float*)d_in[6];
    const float* b_ih2   = (const float*)d_in[7];
    const float* b_hh2   = (const float*)d_in[8];
    const float* w_dense = (const float*)d_in[9];
    const float* b_dense = (const float*)d_in[10];
    float* out = (float*)d_out;

    hipLaunchKernelGGL(lstm_fused_kernel, dim3(256), dim3(1024), 0, stream,
                       x, w_ih1, w_hh1, b_ih1, b_hh1,
                       w_ih2, w_hh2, b_ih2, b_hh2,
                       w_dense, b_dense, out);
    (void)in_sizes; (void)n_in; (void)out_size; (void)d_ws; (void)ws_size;
}

// Round 5
// 4319.496 us; speedup vs baseline: 2.2500x; 2.2500x over previous
//
#include <hip/hip_runtime.h>
#include <cstdint>
#include <cstddef>

#define T_STEPS 512
#define BATCH   1024
#define IN_DIM  178
#define NH1     64
#define NG1     256      // 4*H1
#define NH2     32
#define NG2     128      // 4*H2
#define TCHUNK  4
#define NCHUNK  (T_STEPS / TCHUNK)
#define BPW     4        // batch elements per workgroup
#define XROW    (BATCH * IN_DIM)
#define XS_ROW  (BPW * IN_DIM)   // 712 floats of x per timestep staged in LDS

__device__ __forceinline__ float sigmoidf_(float v) {
    return 1.0f / (1.0f + __expf(-v));
}
__device__ __forceinline__ float tanhf_(float v) {
    return 1.0f - 2.0f / (__expf(2.0f * v) + 1.0f);
}

// Register-budget history: backend pins this kernel at 64 VGPRs (r1-r4) and
// spills the persistent wr1/wr2 arrays whenever peak demand exceeds it.
// r4's peak was the in-proj loop: 16 hoisted global float2 x-loads (32 regs).
// r5 fix: x staged in LDS once per chunk; inner loop reads are wave-uniform
// LDS broadcasts; '#pragma unroll 1' caps in-flight values. Peak ~60 <= 64.

struct __align__(16) SM {
    union {                          // 16 KB — xs aliases xproj: xs live only
        float xproj[TCHUNK][BPW][NG1];  // during in-proj, xproj only during
        float xs[TCHUNK][XS_ROW];       // the recurrent steps (barriers between)
    } x;
    float w1sA[NG1 * 16];            // 16 KB  staging buffer A (swizzled 16B slots)
    union {
        float red[32 * NG2];         // 16 KB  partials: L1 as [16][256], L2 as [32][128]
        float w1sB[NG1 * 16];        //        staging buffer B (aliased)
    } u;
    float h1s[BPW][NH1];             // 1 KB
    float h2s[BPW][NH2];             // 0.5 KB
    float b1s[NG1];
    float b2s[NG2];
    float wds[2 * NH2];
    float bds[4];
};

__device__ __forceinline__ float4 stage_load(const float* __restrict__ w_ih1,
                                             int sg, int k0, bool tail) {
    float4 v;
    if (!tail) {
        const float2* p = (const float2*)(w_ih1 + (size_t)sg * IN_DIM + k0);
        float2 a = p[0], b = p[1];
        v.x = a.x; v.y = a.y; v.z = b.x; v.w = b.y;
    } else {
        v.x = (k0 + 0 < IN_DIM) ? w_ih1[(size_t)sg * IN_DIM + k0 + 0] : 0.0f;
        v.y = (k0 + 1 < IN_DIM) ? w_ih1[(size_t)sg * IN_DIM + k0 + 1] : 0.0f;
        v.z = (k0 + 2 < IN_DIM) ? w_ih1[(size_t)sg * IN_DIM + k0 + 2] : 0.0f;
        v.w = (k0 + 3 < IN_DIM) ? w_ih1[(size_t)sg * IN_DIM + k0 + 3] : 0.0f;
    }
    return v;
}

__device__ __forceinline__ void stage_write(float* buf, int sg, int sslot, float4 v) {
    *(float4*)&buf[sg * 16 + sslot] = v;
}

// FMA over one 16-col k-block. w from swizzled LDS (per-lane b128), x from LDS
// broadcast (wave-uniform address). unroll 1 keeps register pressure bounded.
__device__ __forceinline__ void inproj_compute(const float* __restrict__ xsb,
                                               const float* buf, int kb,
                                               int g1, int swz_r,
                                               float acc[TCHUNK], bool tail) {
    if (tail) {
        // kb=11: only k=176,177 are real (staged wv has zeros beyond; LDS x
        // beyond row end may be garbage/NaN so never multiply it, even by 0).
        const float4 wv = *(const float4*)&buf[g1 * 16 + ((0 ^ swz_r) << 2)];
        const int k = kb * 16;
        #pragma unroll
        for (int tt = 0; tt < TCHUNK; ++tt) {
            const float2 xa = *(const float2*)&xsb[tt * XS_ROW + k];
            acc[tt] += xa.x * wv.x + xa.y * wv.y;
        }
        return;
    }
    #pragma unroll 1
    for (int c4 = 0; c4 < 4; ++c4) {
        const float4 wv = *(const float4*)&buf[g1 * 16 + ((c4 ^ swz_r) << 2)];
        const int k = kb * 16 + c4 * 4;
        #pragma unroll
        for (int tt = 0; tt < TCHUNK; ++tt) {
            const float2 xa = *(const float2*)&xsb[tt * XS_ROW + k];
            const float2 xc = *(const float2*)&xsb[tt * XS_ROW + k + 2];
            acc[tt] += xa.x * wv.x + xa.y * wv.y + xc.x * wv.z + xc.y * wv.w;
        }
    }
}

extern "C" __global__
__attribute__((amdgpu_flat_work_group_size(1024, 1024)))
__attribute__((amdgpu_waves_per_eu(4, 4)))
void lstm_fused_kernel(
    const float* __restrict__ x,
    const float* __restrict__ w_ih1, const float* __restrict__ w_hh1,
    const float* __restrict__ b_ih1, const float* __restrict__ b_hh1,
    const float* __restrict__ w_ih2, const float* __restrict__ w_hh2,
    const float* __restrict__ b_ih2, const float* __restrict__ b_hh2,
    const float* __restrict__ w_dense, const float* __restrict__ b_dense,
    float* __restrict__ out)
{
    __shared__ SM sm;
    const int tid = threadIdx.x;
    const int b0  = blockIdx.x * BPW;

    // ---------------- one-time init ----------------
    if (tid < NG1) sm.b1s[tid] = b_ih1[tid] + b_hh1[tid];
    else if (tid < NG1 + NG2) { int i = tid - NG1; sm.b2s[i] = b_ih2[i] + b_hh2[i]; }
    else if (tid < NG1 + NG2 + 2 * NH2) { int i = tid - NG1 - NG2; sm.wds[i] = w_dense[i]; }
    else if (tid < NG1 + NG2 + 2 * NH2 + 2) { int i = tid - NG1 - NG2 - 2 * NH2; sm.bds[i] = b_dense[i]; }
    if (tid < BPW * NH1) ((float*)sm.h1s)[tid] = 0.0f;
    if (tid < BPW * NH2) ((float*)sm.h2s)[tid] = 0.0f;

    // L1 recurrent weights: thread (g1 = tid&255, kq1 = tid>>8) owns w_hh1[g1][kq1*16 .. +16)
    const int g1  = tid & 255;
    const int kq1 = tid >> 8;
    float wr1[16];
    #pragma unroll
    for (int j = 0; j < 16; ++j) wr1[j] = w_hh1[g1 * NH1 + kq1 * 16 + j];

    // L2 weights (concat [w_ih2 | w_hh2] along k: 96 cols), 8-way k-split:
    // thread (g2 = tid&127, kq2 = tid>>7 in 0..7) owns cols kq2*12 .. +12
    const int g2  = tid & 127;
    const int kq2 = tid >> 7;
    float wr2[12];
    #pragma unroll
    for (int j = 0; j < 12; ++j) {
        int kk = kq2 * 12 + j;
        wr2[j] = (kk < NH1) ? w_ih2[g2 * NH1 + kk] : w_hh2[g2 * NH2 + (kk - NH1)];
    }

    float c1 = 0.0f;  // tid<256: (b=tid>>6, h=tid&63)
    float c2 = 0.0f;  // tid<128: (b=tid>>5, h=tid&31)

    // staging / in-proj index helpers
    const int sg    = tid >> 2;                      // staging row (0..255)
    const int sc4   = tid & 3;                       // logical 16B slot
    const int sslot = ((sc4 ^ ((sg >> 1) & 3)) << 2);// swizzled float offset
    const int bi_   = tid >> 8;                      // in-proj batch slot (0..3)
    const int swz_r = (g1 >> 1) & 3;                 // reader xor key
    const float* xsb = &sm.x.xs[0][0] + bi_ * IN_DIM;// this thread's x row base

    __syncthreads();

    for (int chunk = 0; chunk < NCHUNK; ++chunk) {
        const int t0 = chunk * TCHUNK;

        // ---- stage x chunk into LDS (aliases xproj; prior chunk's xproj
        //      was fully consumed before the barriers that got us here) ----
        #pragma unroll
        for (int tt = 0; tt < TCHUNK; ++tt) {
            const float* src = x + ((size_t)(t0 + tt) * BATCH + b0) * IN_DIM;
            if (tid < XS_ROW) sm.x.xs[tt][tid] = src[tid];
        }

        // ---- prologue: stage w_ih1 kb=0 into A ----
        {
            float4 v0 = stage_load(w_ih1, sg, 0, false);
            stage_write(sm.w1sA, sg, sslot, v0);
        }
        __syncthreads();

        // ================= input projection (double-buffered w stage) =======
        float acc[TCHUNK] = {0.f, 0.f, 0.f, 0.f};

        #pragma unroll 1
        for (int kb2 = 0; kb2 < 6; ++kb2) {
            const int kbA = 2 * kb2;
            const int kbB = 2 * kb2 + 1;
            const bool tailB = (kbB == 11);

            float4 vB = stage_load(w_ih1, sg, kbB * 16 + sc4 * 4, tailB);
            inproj_compute(xsb, sm.w1sA, kbA, g1, swz_r, acc, false);
            stage_write(sm.u.w1sB, sg, sslot, vB);
            __syncthreads();

            const bool haveA2 = (kb2 < 5);
            float4 vA2;
            if (haveA2) vA2 = stage_load(w_ih1, sg, (kbB + 1) * 16 + sc4 * 4, false);
            inproj_compute(xsb, sm.u.w1sB, kbB, g1, swz_r, acc, tailB);
            if (haveA2) stage_write(sm.w1sA, sg, sslot, vA2);
            __syncthreads();
        }

        // xs is dead from here; write xproj over it (same union, post-barrier)
        {
            float b1v = sm.b1s[g1];
            #pragma unroll
            for (int tt = 0; tt < TCHUNK; ++tt)
                sm.x.xproj[tt][bi_][g1] = acc[tt] + b1v;
        }
        __syncthreads();   // protects w1sB(=red) before Phase A writes red

        // ================= TCHUNK recurrent steps =================
        for (int tt = 0; tt < TCHUNK; ++tt) {
            const int t = t0 + tt;

            // ---- Phase A: L1 recurrent partials (all threads); wave-15
            //      stragglers also do the dense head for step t-1 ----
            #pragma unroll
            for (int b = 0; b < BPW; ++b) {
                const float4* hp = (const float4*)&sm.h1s[b][kq1 * 16];  // wave-uniform
                float p = 0.0f;
                #pragma unroll
                for (int j4 = 0; j4 < 4; ++j4) {
                    float4 hv = hp[j4];
                    p += hv.x * wr1[j4 * 4 + 0] + hv.y * wr1[j4 * 4 + 1]
                       + hv.z * wr1[j4 * 4 + 2] + hv.w * wr1[j4 * 4 + 3];
                }
                sm.u.red[(kq1 * 4 + b) * NG1 + g1] = p;   // [16][256]
            }
            if (tid >= 1016) {
                if (t > 0) {   // dense head for t-1 (h2s still holds h2(t-1))
                    const int b = (tid >> 1) & 3, o = tid & 1;
                    float a = sm.bds[o];
                    #pragma unroll
                    for (int k = 0; k < NH2; ++k)
                        a += sigmoidf_(sm.h2s[b][k]) * sm.wds[o * NH2 + k];
                    out[(size_t)(t - 1) * (2 * BATCH) + (size_t)(b0 + b) * 2 + o] = sigmoidf_(a);
                }
            }
            __syncthreads();

            // ---- Phase C: L1 combine + pointwise (tid < 256) ----
            if (tid < 256) {
                const int b = tid >> 6, h = tid & 63;
                float gi = sm.x.xproj[tt][b][h];
                float gf = sm.x.xproj[tt][b][64 + h];
                float gg = sm.x.xproj[tt][b][128 + h];
                float go = sm.x.xproj[tt][b][192 + h];
                #pragma unroll
                for (int kq = 0; kq < 4; ++kq) {
                    const float* r = &sm.u.red[(kq * 4 + b) * NG1];
                    gi += r[h]; gf += r[64 + h]; gg += r[128 + h]; go += r[192 + h];
                }
                float iv = sigmoidf_(gi);
                float fv = sigmoidf_(gf);
                float gv = tanhf_(gg);
                float ov = sigmoidf_(go);
                c1 = fv * c1 + iv * gv;
                sm.h1s[b][h] = ov * tanhf_(c1);
            }
            __syncthreads();

            // ---- Phase B: L2 partials (ALL 1024 threads, 8-way k-split) ----
            #pragma unroll
            for (int b = 0; b < BPW; ++b) {
                float p = 0.0f;
                #pragma unroll
                for (int j4 = 0; j4 < 3; ++j4) {
                    int kk = kq2 * 12 + j4 * 4;
                    float4 v;
                    if (kk < NH1) {
                        float4 hv = *(const float4*)&sm.h1s[b][kk];    // wave-uniform
                        v.x = fmaxf(hv.x, 0.f); v.y = fmaxf(hv.y, 0.f);
                        v.z = fmaxf(hv.z, 0.f); v.w = fmaxf(hv.w, 0.f);
                    } else {
                        v = *(const float4*)&sm.h2s[b][kk - NH1];      // wave-uniform
                    }
                    p += v.x * wr2[j4 * 4 + 0] + v.y * wr2[j4 * 4 + 1]
                       + v.z * wr2[j4 * 4 + 2] + v.w * wr2[j4 * 4 + 3];
                }
                sm.u.red[(kq2 * 4 + b) * NG2 + g2] = p;   // [32][128]
            }
            __syncthreads();

            // ---- Phase C2: L2 combine + pointwise (tid < 128) ----
            if (tid < 128) {
                const int b = tid >> 5, h = tid & 31;
                float gi = sm.b2s[h];
                float gf = sm.b2s[32 + h];
                float gg = sm.b2s[64 + h];
                float go = sm.b2s[96 + h];
                #pragma unroll
                for (int kq = 0; kq < 8; ++kq) {
                    const float* r = &sm.u.red[(kq * 4 + b) * NG2];
                    gi += r[h]; gf += r[32 + h]; gg += r[64 + h]; go += r[96 + h];
                }
                float iv = sigmoidf_(gi);
                float fv = sigmoidf_(gf);
                float gv = tanhf_(gg);
                float ov = sigmoidf_(go);
                c2 = fv * c2 + iv * gv;
                sm.h2s[b][h] = ov * tanhf_(c2);
            }
            __syncthreads();
        }
    }

    // final dense head for t = 511
    if (tid < 8) {
        const int b = tid >> 1, o = tid & 1;
        float a = sm.bds[o];
        #pragma unroll
        for (int k = 0; k < NH2; ++k)
            a += sigmoidf_(sm.h2s[b][k]) * sm.wds[o * NH2 + k];
        out[(size_t)511 * (2 * BATCH) + (size_t)(b0 + b) * 2 + o] = sigmoidf_(a);
    }
}

extern "C" void kernel_launch(void* const* d_in, const int* in_sizes, int n_in,
                              void* d_out, int out_size, void* d_ws, size_t ws_size,
                              hipStream_t stream) {
    const float* x       = (const float*)d_in[0];
    const float* w_ih1   = (const float*)d_in[1];
    const float* w_hh1   = (const float*)d_in[2];
    const float* b_ih1   = (const float*)d_in[3];
    const float* b_hh1   = (const float*)d_in[4];
    const float* w_ih2   = (const float*)d_in[5];
    const float* w_hh2   = (const float*)d_in[6];
    const float* b_ih2   = (const float*)d_in[7];
    const float* b_hh2   = (const float*)d_in[8];
    const float* w_dense = (const float*)d_in[9];
    const float* b_dense = (const float*)d_in[10];
    float* out = (float*)d_out;

    hipLaunchKernelGGL(lstm_fused_kernel, dim3(256), dim3(1024), 0, stream,
                       x, w_ih1, w_hh1, b_ih1, b_hh1,
                       w_ih2, w_hh2, b_ih2, b_hh2,
                       w_dense, b_dense, out);
    (void)in_sizes; (void)n_in; (void)out_size; (void)d_ws; (void)ws_size;
}